// Round 8
// baseline (293.898 us; speedup 1.0000x reference)
//
#include <hip/hip_runtime.h>
#include <math.h>

#define TPB 256
#define CTPB 1024
#define KTPB 512

// ---------- complex helpers ----------
__device__ __forceinline__ float2 cmul(float2 a, float2 b) {
    return make_float2(a.x * b.x - a.y * b.y, a.x * b.y + a.y * b.x);
}
__device__ __forceinline__ float2 cdivf(float2 a, float2 b) {
    float inv = 1.0f / (b.x * b.x + b.y * b.y);
    return make_float2((a.x * b.x + a.y * b.y) * inv, (a.y * b.x - a.x * b.y) * inv);
}
__device__ __forceinline__ float2 cadd(float2 a, float2 b) { return make_float2(a.x + b.x, a.y + b.y); }
__device__ __forceinline__ float2 csub(float2 a, float2 b) { return make_float2(a.x - b.x, a.y - b.y); }
__device__ __forceinline__ float2 mul_i(float2 a, float d) {  // a * (i*d)
    return make_float2(-d * a.y, d * a.x);
}
__device__ __forceinline__ int brev11(int x) { return (int)(__brev((unsigned)x) >> 21); }
// base-8 digit reversal of a 12-bit index (4 digits)
__device__ __forceinline__ int rev8(int x) {
    return ((x & 7) << 9) | (((x >> 3) & 7) << 6) | (((x >> 6) & 7) << 3) | ((x >> 9) & 7);
}
// LDS bank swizzles (GF(2)-linear: swz(a^b)==swz(a)^swz(b))
__device__ __forceinline__ int swz(int i) { return i ^ ((i >> 4) & 15) ^ ((i >> 8) & 15); }
__device__ __forceinline__ int swz13(int i) {
    return i ^ ((i >> 4) & 15) ^ ((i >> 8) & 15) ^ ((i >> 12) & 1);
}

// ---------- 8-point DFT cores ----------
__device__ __forceinline__ void dft8(const float2* x, float2* y, float d) {
    const float r = 0.70710678118f;
    float2 s0 = cadd(x[0], x[4]), t0 = csub(x[0], x[4]);
    float2 s1 = cadd(x[1], x[5]), t1 = csub(x[1], x[5]);
    float2 s2 = cadd(x[2], x[6]), t2 = csub(x[2], x[6]);
    float2 s3 = cadd(x[3], x[7]), t3 = csub(x[3], x[7]);
    t1 = cmul(t1, make_float2(r, d * r));
    t2 = mul_i(t2, d);
    t3 = cmul(t3, make_float2(-r, d * r));
    float2 u0 = cadd(s0, s2), v0 = csub(s0, s2);
    float2 u1 = cadd(s1, s3), v1 = mul_i(csub(s1, s3), d);
    y[0] = cadd(u0, u1); y[4] = csub(u0, u1);
    y[2] = cadd(v0, v1); y[6] = csub(v0, v1);
    float2 p0 = cadd(t0, t2), q0 = csub(t0, t2);
    float2 p1 = cadd(t1, t3), q1 = mul_i(csub(t1, t3), d);
    y[1] = cadd(p0, p1); y[5] = csub(p0, p1);
    y[3] = cadd(q0, q1); y[7] = csub(q0, q1);
}

// dft8 with x[4..7] == 0 (zero-padded upper half)
__device__ __forceinline__ void dft8z(float2 x0, float2 x1, float2 x2, float2 x3,
                                      float2* y, float d) {
    const float r = 0.70710678118f;
    float2 u0 = cadd(x0, x2), v0 = csub(x0, x2);
    float2 u1 = cadd(x1, x3), v1 = mul_i(csub(x1, x3), d);
    float2 t1 = cmul(x1, make_float2(r, d * r));
    float2 t2 = mul_i(x2, d);
    float2 t3 = cmul(x3, make_float2(-r, d * r));
    float2 p0 = cadd(x0, t2), q0 = csub(x0, t2);
    float2 p1 = cadd(t1, t3), q1 = mul_i(csub(t1, t3), d);
    y[0] = cadd(u0, u1); y[4] = csub(u0, u1);
    y[2] = cadd(v0, v1); y[6] = csub(v0, v1);
    y[1] = cadd(p0, p1); y[5] = csub(p0, p1);
    y[3] = cadd(q0, q1); y[7] = csub(q0, q1);
}

// dft8 computing only outputs y[0..3] — for the discarded tail
__device__ __forceinline__ void dft8_lo(const float2* x, float2* y, float d) {
    const float r = 0.70710678118f;
    float2 s0 = cadd(x[0], x[4]), t0 = csub(x[0], x[4]);
    float2 s1 = cadd(x[1], x[5]), t1 = csub(x[1], x[5]);
    float2 s2 = cadd(x[2], x[6]), t2 = csub(x[2], x[6]);
    float2 s3 = cadd(x[3], x[7]), t3 = csub(x[3], x[7]);
    t1 = cmul(t1, make_float2(r, d * r));
    t2 = mul_i(t2, d);
    t3 = cmul(t3, make_float2(-r, d * r));
    float2 u0 = cadd(s0, s2), v0 = csub(s0, s2);
    float2 u1 = cadd(s1, s3), v1 = mul_i(csub(s1, s3), d);
    y[0] = cadd(u0, u1);
    y[2] = cadd(v0, v1);
    float2 p0 = cadd(t0, t2), q0 = csub(t0, t2);
    float2 p1 = cadd(t1, t3), q1 = mul_i(csub(t1, t3), d);
    y[1] = cadd(p0, p1);
    y[3] = cadd(q0, q1);
}

// ---------- radix-8 stages for conv2 (1 butterfly/thread, N=8192, NT=1024) ----------
template <int HB, int DIR>
__device__ __forceinline__ void dif13(float2* s, int tid) {
    __syncthreads();
    const int h = 1 << HB;
    int j = tid & (h - 1);
    int base = ((tid >> HB) << (HB + 3)) + j;
    int s0 = swz13(base);
    float2 x[8];
#pragma unroll
    for (int k = 0; k < 8; ++k) x[k] = s[s0 ^ swz13(k << HB)];
    float2 y[8];
    dft8(x, y, (float)DIR);
    float ang = (float)DIR * 6.283185307179586f / (float)(h << 3) * (float)j;
    float c, sn;
    __sincosf(ang, &sn, &c);
    float2 w = make_float2(c, sn), wm = w;
    s[s0] = y[0];
#pragma unroll
    for (int m = 1; m < 8; ++m) {
        s[s0 ^ swz13(m << HB)] = cmul(wm, y[m]);
        wm = cmul(wm, w);
    }
}

template <int HB, int DIR>
__device__ __forceinline__ void dit13(float2* s, int tid) {
    __syncthreads();
    const int h = 1 << HB;
    int j = tid & (h - 1);
    int base = ((tid >> HB) << (HB + 3)) + j;
    int s0 = swz13(base);
    float ang = (float)DIR * 6.283185307179586f / (float)(h << 3) * (float)j;
    float c, sn;
    __sincosf(ang, &sn, &c);
    float2 w = make_float2(c, sn);
    float2 x[8];
    x[0] = s[s0];
    float2 wm = w;
#pragma unroll
    for (int k = 1; k < 8; ++k) {
        x[k] = cmul(wm, s[s0 ^ swz13(k << HB)]);
        wm = cmul(wm, w);
    }
    float2 y[8];
    dft8(x, y, (float)DIR);
#pragma unroll
    for (int m = 0; m < 8; ++m) s[s0 ^ swz13(m << HB)] = y[m];
}

// ---------- generic radix-8 DIF (for kprep), with h=1 twiddle skip ----------
template <int LOGN, int NT>
__device__ void fft8_dif(float2* s, int tid, float dir) {
    const int N = 1 << LOGN;
#pragma unroll
    for (int hb = LOGN - 3; hb >= 0; hb -= 3) {
        const int h = 1 << hb;
        const float astep = dir * 6.283185307179586f / (float)(h << 3);
        __syncthreads();
#pragma unroll
        for (int it = 0; it < (N >> 3) / NT; ++it) {
            const int b = tid + it * NT;
            int j = b & (h - 1);
            int base = ((b >> hb) << (hb + 3)) + j;
            int s0 = swz(base);
            float2 x[8];
#pragma unroll
            for (int k = 0; k < 8; ++k) x[k] = s[s0 ^ swz(k << hb)];
            float2 y[8];
            dft8(x, y, dir);
            if (hb != 0) {  // folds: hb is unroll-constant
                float ang = astep * (float)j;
                float c, sn;
                __sincosf(ang, &sn, &c);
                float2 w = make_float2(c, sn), wm = w;
                s[s0] = y[0];
#pragma unroll
                for (int m = 1; m < 8; ++m) {
                    s[s0 ^ swz(m << hb)] = cmul(wm, y[m]);
                    wm = cmul(wm, w);
                }
            } else {
#pragma unroll
                for (int m = 0; m < 8; ++m) s[s0 ^ swz(m << hb)] = y[m];
            }
        }
    }
    __syncthreads();
}

// ---------- radix-2 DIF (unswizzled), for the 2048-pt kernel inverse only ----------
template <int LOGN, int NT>
__device__ void fft_dif2(float2* s, int tid, float dir) {
    const int N = 1 << LOGN;
    for (int st = LOGN - 1; st >= 0; --st) {
        __syncthreads();
        int half = 1 << st;
        for (int b = tid; b < (N >> 1); b += NT) {
            int j  = b & (half - 1);
            int i0 = ((b >> st) << (st + 1)) + j;
            int i1 = i0 + half;
            float2 u = s[i0], v = s[i1];
            float2 d = make_float2(u.x - v.x, u.y - v.y);
            s[i0] = make_float2(u.x + v.x, u.y + v.y);
            if (half > 1) {
                float ang = dir * 3.14159265358979f * (float)j / (float)half;
                float c, sn;
                __sincosf(ang, &sn, &c);
                s[i1] = cmul(make_float2(c, sn), d);
            } else {
                s[i1] = d;
            }
        }
    }
    __syncthreads();
}

// ---------- prep (heterogeneous): blocks 0..511 = kf+kprep; 512..4607 = transpose_in.
// kprep now emits the FULL 8192-bin kernel spectrum (Hermitian-extended, 1/8192
// pre-folded) in conv2's mixed-radix slot order:
//   slot q holds K_full[perm13(q)],  perm13(q) = q[12:10] + 8*q[9:7] + 64*q[6:4]
//                                              + 512*q[3:1] + 4096*q[0]
//   K_full[j] = X[j] (j<=4096), conj(X[8192-j]) (j>4096); X from Hermitian unpack of Y. ----------
__global__ __launch_bounds__(KTPB) void prep_kernel(
    const float* __restrict__ log_dt, const float* __restrict__ w_ri,
    const float* __restrict__ Bri, const float* __restrict__ Cri,
    const float* __restrict__ x, float2* __restrict__ Kt, float* __restrict__ xt) {
    __shared__ float2 s[4096];
    __shared__ float2 kf_last;
    __shared__ float2 wds[32];
    __shared__ float aab[4][32], rab[4][32];
    __shared__ float qn[32], pn[32];
    const int tid = threadIdx.x;

    if (blockIdx.x >= 512) {
        // ---- transpose_in tile (512 threads, 2 iterations), tile buffer aliases s[]
        float* tile = (float*)s;                       // [64][65] floats = 16.6 KB
        const int tl_id = blockIdx.x - 512;            // 0..4095
        const int b  = tl_id >> 9;
        const int rem = tl_id & 511;
        const int t0 = (rem >> 3) << 6;                // 64 t-tiles
        const int h0 = (rem & 7) << 6;                 // 8 h-tiles
        const float4* xv = (const float4*)(x + ((size_t)b * 4096 + t0) * 512 + h0);
#pragma unroll
        for (int i = 0; i < 2; ++i) {
            int idx = tid + KTPB * i;                  // 0..1023
            int tl = idx >> 4, hq = idx & 15;
            float4 v = xv[(size_t)tl * 128 + hq];
            tile[tl * 65 + hq * 4 + 0] = v.x; tile[tl * 65 + hq * 4 + 1] = v.y;
            tile[tl * 65 + hq * 4 + 2] = v.z; tile[tl * 65 + hq * 4 + 3] = v.w;
        }
        __syncthreads();
        float* xo = xt + ((size_t)(b * 512 + h0)) * 4096 + t0;
#pragma unroll
        for (int i = 0; i < 2; ++i) {
            int idx = tid + KTPB * i;
            int hl = idx >> 4, tq = idx & 15;
            float4 v = make_float4(tile[(tq * 4 + 0) * 65 + hl], tile[(tq * 4 + 1) * 65 + hl],
                                   tile[(tq * 4 + 2) * 65 + hl], tile[(tq * 4 + 3) * 65 + hl]);
            ((float4*)(xo + (size_t)hl * 4096))[tq] = v;
        }
        return;
    }

    // ---- kf part (identical math; spectrum stored in kfs = s[2048..4096) + kf_last)
    const int hh = blockIdx.x;
    float2* kfs = s + 2048;
    const float dt = expf(log_dt[hh]);
    if (tid < 32) {
        float wr = w_ri[2 * tid] * dt, wi = w_ri[2 * tid + 1] * dt;
        wds[tid] = make_float2(wr, wi);
        qn[tid]  = wr * wr + wi * wi;
        pn[tid]  = -2.0f * wr;
    }
    __syncthreads();
    if (tid < 128) {
        int a = tid >> 6, b = (tid >> 5) & 1, n = tid & 31;
        const float* Cp = Cri + (((hh * 2 + a) * 32) + n) * 2;
        const float* Bp = Bri + (((hh * 2 + b) * 32) + n) * 2;
        float Cr = Cp[0], Ci = Cp[1], Br = Bp[0], Bi = Bp[1];
        float2 v = make_float2(Cr * Br + Ci * Bi, Cr * Bi - Ci * Br);  // conj(C)*B
        float2 wd = wds[n];
        aab[a * 2 + b][n] = -2.0f * (v.x * wd.x + v.y * wd.y);
        rab[a * 2 + b][n] = 2.0f * v.x;
    }
    __syncthreads();
    for (int f = tid; f < 2049; f += KTPB) {
        float th = (6.283185307179586f / 4096.0f) * (float)f;
        float cf = cosf(th), sf = sinf(th);
        float2 den = make_float2(1.0f + cf, -sf);      // 1 + freq
        float zt  = 2.0f * tanf(0.5f * th);
        float zt2 = zt * zt;
        float2 r00 = make_float2(0.f, 0.f), r01 = r00, r10 = r00, r11 = r00;
        for (int n = 0; n < 32; ++n) {
            float c   = qn[n] - zt2;
            float d   = pn[n] * zt;
            float inv = 1.0f / (c * c + d * d);
            float cc = c * inv, dd = d * inv;
            float a0 = aab[0][n], b0 = rab[0][n] * zt;
            r00.x += a0 * cc + b0 * dd; r00.y += b0 * cc - a0 * dd;
            float a1 = aab[1][n], b1 = rab[1][n] * zt;
            r01.x += a1 * cc + b1 * dd; r01.y += b1 * cc - a1 * dd;
            float a2 = aab[2][n], b2 = rab[2][n] * zt;
            r10.x += a2 * cc + b2 * dd; r10.y += b2 * cc - a2 * dd;
            float a3 = aab[3][n], b3 = rab[3][n] * zt;
            r11.x += a3 * cc + b3 * dd; r11.y += b3 * cc - a3 * dd;
        }
        r00.x *= dt; r00.y *= dt; r01.x *= dt; r01.y *= dt;
        r10.x *= dt; r10.y *= dt; r11.x *= dt; r11.y *= dt;
        float2 q  = cdivf(cmul(r01, r10), make_float2(1.0f + r11.x, r11.y));
        float2 k0 = make_float2(r00.x - q.x, r00.y - q.y);
        float2 kv = cmul(k0, cdivf(make_float2(2.0f, 0.0f), den));
        if (f < 2048) kfs[f] = kv; else kf_last = kv;
    }
    __syncthreads();

    // ---- kprep part: reads spectrum from s[2048..] / kf_last, writes s[0..2048)
    for (int m = tid; m < 2048; m += KTPB) {
        float2 Xm = kfs[m];
        float2 Xc = (m == 0) ? kf_last : kfs[2048 - m];
        if (m == 0) { Xm.y = 0.0f; Xc.y = 0.0f; }
        float2 A  = make_float2(Xm.x + Xc.x, Xm.y - Xc.y);
        float2 Bv = make_float2(Xm.x - Xc.x, Xm.y + Xc.y);
        float ang = (3.14159265358979f / 2048.0f) * (float)m;
        float c, sn;
        __sincosf(ang, &sn, &c);
        float2 O = cmul(make_float2(c, sn), Bv);
        s[m] = make_float2(0.5f * (A.x - O.y), 0.5f * (A.y + O.x));
    }
    fft_dif2<11, KTPB>(s, tid, +1.0f);  // inverse, natural-in -> bitrev-out (unswizzled)
    float2 reg[4];
    const float sc = 1.0f / 2048.0f;
#pragma unroll
    for (int i = 0; i < 4; ++i) {
        int t = tid + KTPB * i;  // 0..2047
        float2 v = s[brev11(t)];
        reg[i] = make_float2(v.x * sc, v.y * sc);
    }
    __syncthreads();
#pragma unroll
    for (int i = 0; i < 4; ++i) {
        int t = tid + KTPB * i;
        s[swz(t)]        = reg[i];
        s[swz(t + 2048)] = make_float2(0.f, 0.f);   // reclaims the dead kfs region
    }
    fft8_dif<12, KTPB>(s, tid, -1.0f);  // slot p holds Y[rev8(p)]
    float2* K2 = Kt + ((size_t)hh << 13);
    const float isc = 1.0f / 8192.0f;
    const float2 Y0 = s[swz(0)];
    const float nyq = Y0.x - Y0.y;                  // X[4096], real
    for (int q = tid; q < 8192; q += KTPB) {
        int j13 = ((q >> 10) & 7) | (((q >> 7) & 7) << 3) | (((q >> 4) & 7) << 6)
                | (((q >> 1) & 7) << 9) | ((q & 1) << 12);
        int cj = j13 > 4096;
        int j  = cj ? 8192 - j13 : j13;
        float2 X;
        if (j == 4096) {
            X = make_float2(nyq, 0.0f);
        } else {
            int p  = rev8(j);
            int pc = rev8((4096 - j) & 4095);
            float2 Yj = s[swz(p)], Yc = s[swz(pc)];
            float2 A  = make_float2(Yj.x + Yc.x, Yj.y - Yc.y);
            float2 Bv = make_float2(Yj.x - Yc.x, Yj.y + Yc.y);
            float ang = -(3.14159265358979f / 4096.0f) * (float)j;
            float c, sn;
            __sincosf(ang, &sn, &c);
            float2 t2 = cmul(make_float2(c, sn), make_float2(Bv.y, -Bv.x));
            X = make_float2(0.5f * (A.x + t2.x), 0.5f * (A.y + t2.y));
        }
        if (cj) X.y = -X.y;
        K2[q] = make_float2(X.x * isc, X.y * isc);
    }
}

// ---------- conv2: TWO rows per block via complex packing z = x1 + i*x2.
// y1+i*y2 = ifft8192(K * fft8192(z)) — K Hermitian => both convs in one transform,
// pointwise is a single cmul/bin (no Hermitian unpack/pair logic at all).
// N=8192: radix-8 stages h=1024(regs,dft8z),128,16,2 + radix-2 h=1; inverse mirrored,
// final h=1024 stage keeps only m<=3 (t<4096) via dft8_lo. 1024 thr, 64KB LDS ->
// 2 blocks/CU = 32 waves/CU (same occupancy as the 1-row version). ----------
__global__ __launch_bounds__(CTPB) void conv_kernel(const float* xt,
                                                    const float2* __restrict__ Kt,
                                                    const float* __restrict__ Dv,
                                                    float* yt) {
    __shared__ float2 s[8192];
    const int bp  = blockIdx.x >> 9;        // batch pair 0..3
    const int hch = blockIdx.x & 511;
    const int tid = threadIdx.x;            // 0..1023
    const int stid = swz13(tid);
    float* r1 = (float*)(xt + ((size_t)(bp * 1024 + hch)) * 4096);        // row (2bp, h)
    float* r2 = r1 + (size_t)512 * 4096;                                   // row (2bp+1, h)

    // ---- stage A fwd (DIF h=1024) in registers; upper half zero pad -> dft8z
    {
        float2 z[4];
#pragma unroll
        for (int k = 0; k < 4; ++k) {
            int t = tid + (k << 10);
            z[k] = make_float2(r1[t], r2[t]);
        }
        float2 y[8];
        dft8z(z[0], z[1], z[2], z[3], y, -1.0f);
        float ang = -(6.283185307179586f / 8192.0f) * (float)tid;
        float c, sn;
        __sincosf(ang, &sn, &c);
        float2 w = make_float2(c, sn), wm = w;
        s[stid] = y[0];
#pragma unroll
        for (int m = 1; m < 8; ++m) {
            s[stid ^ swz13(m << 10)] = cmul(wm, y[m]);
            wm = cmul(wm, w);
        }
    }
    dif13<7, -1>(s, tid);   // h=128
    dif13<4, -1>(s, tid);   // h=16
    dif13<1, -1>(s, tid);   // h=2
    __syncthreads();
    // ---- stage E fwd (radix-2, h=1, no twiddle): pairs (2b, 2b+1), thread-exclusive
#pragma unroll
    for (int it = 0; it < 4; ++it) {
        int b  = tid + (it << 10);
        int i0 = swz13(b << 1), i1 = swz13((b << 1) | 1);
        float2 u = s[i0], v = s[i1];
        s[i0] = cadd(u, v);
        s[i1] = csub(u, v);
    }
    __syncthreads();
    // ---- pointwise: one cmul per bin (K pre-permuted + 1/8192 pre-folded)
    const float2* K = Kt + ((size_t)hch << 13);
#pragma unroll
    for (int i = 0; i < 8; ++i) {
        int p  = tid + (i << 10);
        int sp = stid ^ swz13(i << 10);
        s[sp] = cmul(s[sp], K[p]);
    }
    __syncthreads();
    // ---- stage E inv (radix-2, h=1)
#pragma unroll
    for (int it = 0; it < 4; ++it) {
        int b  = tid + (it << 10);
        int i0 = swz13(b << 1), i1 = swz13((b << 1) | 1);
        float2 u = s[i0], v = s[i1];
        s[i0] = cadd(u, v);
        s[i1] = csub(u, v);
    }
    dit13<1, 1>(s, tid);    // h=2
    dit13<4, 1>(s, tid);    // h=16
    dit13<7, 1>(s, tid);    // h=128
    __syncthreads();
    // ---- stage A inv (DIT h=1024) in registers; keep t<4096 (m<=3); fuse D*x skip
    {
        float ang = (6.283185307179586f / 8192.0f) * (float)tid;
        float c, sn;
        __sincosf(ang, &sn, &c);
        float2 w = make_float2(c, sn);
        float2 x[8];
        x[0] = s[stid];
        float2 wm = w;
#pragma unroll
        for (int k = 1; k < 8; ++k) {
            x[k] = cmul(wm, s[stid ^ swz13(k << 10)]);
            wm = cmul(wm, w);
        }
        float2 y[4];
        dft8_lo(x, y, 1.0f);
        const float D = Dv[hch];
#pragma unroll
        for (int m = 0; m < 4; ++m) {
            int t = tid + (m << 10);
            float x1 = r1[t], x2 = r2[t];   // re-read own rows; in-place per-element safe
            r1[t] = y[m].x + D * x1;        // (1/8192 pre-folded into K)
            r2[t] = y[m].y + D * x2;
        }
    }
}

// ---------- transpose out (pure): out[b,t,h] = yt[(b*512+h),t] ----------
__global__ __launch_bounds__(TPB) void transpose_out(const float* __restrict__ yt,
                                                     float* __restrict__ out) {
    __shared__ float tile[64][65];
    const int b = blockIdx.z, t0 = blockIdx.y * 64, h0 = blockIdx.x * 64;
    const int tid = threadIdx.x;
    const float* yp = yt + ((size_t)(b * 512 + h0)) * 4096 + t0;
#pragma unroll
    for (int i = 0; i < 4; ++i) {
        int idx = tid + TPB * i;
        int hl = idx >> 4, tq = idx & 15;
        float4 v = ((const float4*)(yp + (size_t)hl * 4096))[tq];
        tile[tq * 4 + 0][hl] = v.x; tile[tq * 4 + 1][hl] = v.y;
        tile[tq * 4 + 2][hl] = v.z; tile[tq * 4 + 3][hl] = v.w;
    }
    __syncthreads();
    float4* ov = (float4*)(out + ((size_t)b * 4096 + t0) * 512 + h0);
#pragma unroll
    for (int i = 0; i < 4; ++i) {
        int idx = tid + TPB * i;
        int tl = idx >> 4, hq = idx & 15;
        float4 v = make_float4(tile[tl][4 * hq + 0], tile[tl][4 * hq + 1],
                               tile[tl][4 * hq + 2], tile[tl][4 * hq + 3]);
        ov[(size_t)tl * 128 + hq] = v;
    }
}

extern "C" void kernel_launch(void* const* d_in, const int* in_sizes, int n_in,
                              void* d_out, int out_size, void* d_ws, size_t ws_size,
                              hipStream_t stream) {
    (void)in_sizes; (void)n_in; (void)out_size; (void)ws_size;
    const float* x      = (const float*)d_in[0];  // [8,4096,512]
    const float* log_dt = (const float*)d_in[1];  // [512]
    const float* w_ri   = (const float*)d_in[2];  // [32,2]
    const float* Bri    = (const float*)d_in[3];  // [512,2,32,2]
    const float* Cri    = (const float*)d_in[4];  // [512,2,32,2]
    const float* Dv     = (const float*)d_in[5];  // [512]
    float* out = (float*)d_out;

    char* ws = (char*)d_ws;
    float*  xt = (float*)(ws);                  // 8*512*4096*4 = 67,108,864 B (reused as yt)
    float2* Kt = (float2*)(ws + 67108864);      // 512*8192*8   = 33,554,432 B (end 96 MiB)

    prep_kernel<<<512 + 4096, KTPB, 0, stream>>>(log_dt, w_ri, Bri, Cri, x, Kt, xt);
    conv_kernel<<<2048, CTPB, 0, stream>>>(xt, Kt, Dv, xt);  // y(+skip) overwrites xt rows
    transpose_out<<<dim3(8, 64, 8), TPB, 0, stream>>>(xt, out);
}

// Round 9
// 275.868 us; speedup vs baseline: 1.0654x; 1.0654x over previous
//
#include <hip/hip_runtime.h>
#include <math.h>

#define TPB 256
#define CTPB 1024
#define KTPB 512

// ---------- complex helpers ----------
__device__ __forceinline__ float2 cmul(float2 a, float2 b) {
    return make_float2(a.x * b.x - a.y * b.y, a.x * b.y + a.y * b.x);
}
__device__ __forceinline__ float2 cdivf(float2 a, float2 b) {
    float inv = 1.0f / (b.x * b.x + b.y * b.y);
    return make_float2((a.x * b.x + a.y * b.y) * inv, (a.y * b.x - a.x * b.y) * inv);
}
__device__ __forceinline__ float2 cadd(float2 a, float2 b) { return make_float2(a.x + b.x, a.y + b.y); }
__device__ __forceinline__ float2 csub(float2 a, float2 b) { return make_float2(a.x - b.x, a.y - b.y); }
__device__ __forceinline__ float2 mul_i(float2 a, float d) {  // a * (i*d)
    return make_float2(-d * a.y, d * a.x);
}
__device__ __forceinline__ int brev11(int x) { return (int)(__brev((unsigned)x) >> 21); }
// base-8 digit reversal of a 12-bit index (4 digits)
__device__ __forceinline__ int rev8(int x) {
    return ((x & 7) << 9) | (((x >> 3) & 7) << 6) | (((x >> 6) & 7) << 3) | ((x >> 9) & 7);
}
// LDS bank swizzles (GF(2)-linear: swz(a^b)==swz(a)^swz(b); swz13 preserves bit 0)
__device__ __forceinline__ int swz(int i) { return i ^ ((i >> 4) & 15) ^ ((i >> 8) & 15); }
__device__ __forceinline__ int swz13(int i) {
    return i ^ ((i >> 4) & 15) ^ ((i >> 8) & 15) ^ ((i >> 12) & 1);
}

// ---------- 8-point DFT cores ----------
__device__ __forceinline__ void dft8(const float2* x, float2* y, float d) {
    const float r = 0.70710678118f;
    float2 s0 = cadd(x[0], x[4]), t0 = csub(x[0], x[4]);
    float2 s1 = cadd(x[1], x[5]), t1 = csub(x[1], x[5]);
    float2 s2 = cadd(x[2], x[6]), t2 = csub(x[2], x[6]);
    float2 s3 = cadd(x[3], x[7]), t3 = csub(x[3], x[7]);
    t1 = cmul(t1, make_float2(r, d * r));
    t2 = mul_i(t2, d);
    t3 = cmul(t3, make_float2(-r, d * r));
    float2 u0 = cadd(s0, s2), v0 = csub(s0, s2);
    float2 u1 = cadd(s1, s3), v1 = mul_i(csub(s1, s3), d);
    y[0] = cadd(u0, u1); y[4] = csub(u0, u1);
    y[2] = cadd(v0, v1); y[6] = csub(v0, v1);
    float2 p0 = cadd(t0, t2), q0 = csub(t0, t2);
    float2 p1 = cadd(t1, t3), q1 = mul_i(csub(t1, t3), d);
    y[1] = cadd(p0, p1); y[5] = csub(p0, p1);
    y[3] = cadd(q0, q1); y[7] = csub(q0, q1);
}

// dft8 with x[4..7] == 0 (zero-padded upper half)
__device__ __forceinline__ void dft8z(float2 x0, float2 x1, float2 x2, float2 x3,
                                      float2* y, float d) {
    const float r = 0.70710678118f;
    float2 u0 = cadd(x0, x2), v0 = csub(x0, x2);
    float2 u1 = cadd(x1, x3), v1 = mul_i(csub(x1, x3), d);
    float2 t1 = cmul(x1, make_float2(r, d * r));
    float2 t2 = mul_i(x2, d);
    float2 t3 = cmul(x3, make_float2(-r, d * r));
    float2 p0 = cadd(x0, t2), q0 = csub(x0, t2);
    float2 p1 = cadd(t1, t3), q1 = mul_i(csub(t1, t3), d);
    y[0] = cadd(u0, u1); y[4] = csub(u0, u1);
    y[2] = cadd(v0, v1); y[6] = csub(v0, v1);
    y[1] = cadd(p0, p1); y[5] = csub(p0, p1);
    y[3] = cadd(q0, q1); y[7] = csub(q0, q1);
}

// dft8 computing only outputs y[0..3] — for the discarded tail
__device__ __forceinline__ void dft8_lo(const float2* x, float2* y, float d) {
    const float r = 0.70710678118f;
    float2 s0 = cadd(x[0], x[4]), t0 = csub(x[0], x[4]);
    float2 s1 = cadd(x[1], x[5]), t1 = csub(x[1], x[5]);
    float2 s2 = cadd(x[2], x[6]), t2 = csub(x[2], x[6]);
    float2 s3 = cadd(x[3], x[7]), t3 = csub(x[3], x[7]);
    t1 = cmul(t1, make_float2(r, d * r));
    t2 = mul_i(t2, d);
    t3 = cmul(t3, make_float2(-r, d * r));
    float2 u0 = cadd(s0, s2), v0 = csub(s0, s2);
    float2 u1 = cadd(s1, s3), v1 = mul_i(csub(s1, s3), d);
    y[0] = cadd(u0, u1);
    y[2] = cadd(v0, v1);
    float2 p0 = cadd(t0, t2), q0 = csub(t0, t2);
    float2 p1 = cadd(t1, t3), q1 = mul_i(csub(t1, t3), d);
    y[1] = cadd(p0, p1);
    y[3] = cadd(q0, q1);
}

// ---------- radix-8 stages for conv2 (1 butterfly/thread, N=8192, NT=1024) ----------
// twiddle powers as a depth-3 tree (w2=w^2, w4=w2^2, w7=w4*w3) — 2-block/CU occupancy
// can't hide a 7-deep serial cmul chain (r8 lesson: VALUBusy 54%)
template <int HB, int DIR>
__device__ __forceinline__ void dif13(float2* s, int tid) {
    __syncthreads();
    const int h = 1 << HB;
    int j = tid & (h - 1);
    int base = ((tid >> HB) << (HB + 3)) + j;
    int s0 = swz13(base);
    float2 x[8];
#pragma unroll
    for (int k = 0; k < 8; ++k) x[k] = s[s0 ^ swz13(k << HB)];
    float2 y[8];
    dft8(x, y, (float)DIR);
    float ang = (float)DIR * 6.283185307179586f / (float)(h << 3) * (float)j;
    float c, sn;
    __sincosf(ang, &sn, &c);
    float2 w1 = make_float2(c, sn);
    float2 w2 = cmul(w1, w1), w3 = cmul(w2, w1), w4 = cmul(w2, w2);
    s[s0]                    = y[0];
    s[s0 ^ swz13(1 << HB)]   = cmul(w1, y[1]);
    s[s0 ^ swz13(2 << HB)]   = cmul(w2, y[2]);
    s[s0 ^ swz13(3 << HB)]   = cmul(w3, y[3]);
    s[s0 ^ swz13(4 << HB)]   = cmul(w4, y[4]);
    s[s0 ^ swz13(5 << HB)]   = cmul(cmul(w4, w1), y[5]);
    s[s0 ^ swz13(6 << HB)]   = cmul(cmul(w4, w2), y[6]);
    s[s0 ^ swz13(7 << HB)]   = cmul(cmul(w4, w3), y[7]);
}

template <int HB, int DIR>
__device__ __forceinline__ void dit13(float2* s, int tid) {
    __syncthreads();
    const int h = 1 << HB;
    int j = tid & (h - 1);
    int base = ((tid >> HB) << (HB + 3)) + j;
    int s0 = swz13(base);
    float ang = (float)DIR * 6.283185307179586f / (float)(h << 3) * (float)j;
    float c, sn;
    __sincosf(ang, &sn, &c);
    float2 w1 = make_float2(c, sn);
    float2 w2 = cmul(w1, w1), w3 = cmul(w2, w1), w4 = cmul(w2, w2);
    float2 x[8];
    x[0] = s[s0];
    x[1] = cmul(w1, s[s0 ^ swz13(1 << HB)]);
    x[2] = cmul(w2, s[s0 ^ swz13(2 << HB)]);
    x[3] = cmul(w3, s[s0 ^ swz13(3 << HB)]);
    x[4] = cmul(w4, s[s0 ^ swz13(4 << HB)]);
    x[5] = cmul(cmul(w4, w1), s[s0 ^ swz13(5 << HB)]);
    x[6] = cmul(cmul(w4, w2), s[s0 ^ swz13(6 << HB)]);
    x[7] = cmul(cmul(w4, w3), s[s0 ^ swz13(7 << HB)]);
    float2 y[8];
    dft8(x, y, (float)DIR);
#pragma unroll
    for (int m = 0; m < 8; ++m) s[s0 ^ swz13(m << HB)] = y[m];
}

// ---------- generic radix-8 DIF (for kprep), with h=1 twiddle skip ----------
template <int LOGN, int NT>
__device__ void fft8_dif(float2* s, int tid, float dir) {
    const int N = 1 << LOGN;
#pragma unroll
    for (int hb = LOGN - 3; hb >= 0; hb -= 3) {
        const int h = 1 << hb;
        const float astep = dir * 6.283185307179586f / (float)(h << 3);
        __syncthreads();
#pragma unroll
        for (int it = 0; it < (N >> 3) / NT; ++it) {
            const int b = tid + it * NT;
            int j = b & (h - 1);
            int base = ((b >> hb) << (hb + 3)) + j;
            int s0 = swz(base);
            float2 x[8];
#pragma unroll
            for (int k = 0; k < 8; ++k) x[k] = s[s0 ^ swz(k << hb)];
            float2 y[8];
            dft8(x, y, dir);
            if (hb != 0) {  // folds: hb is unroll-constant
                float ang = astep * (float)j;
                float c, sn;
                __sincosf(ang, &sn, &c);
                float2 w = make_float2(c, sn), wm = w;
                s[s0] = y[0];
#pragma unroll
                for (int m = 1; m < 8; ++m) {
                    s[s0 ^ swz(m << hb)] = cmul(wm, y[m]);
                    wm = cmul(wm, w);
                }
            } else {
#pragma unroll
                for (int m = 0; m < 8; ++m) s[s0 ^ swz(m << hb)] = y[m];
            }
        }
    }
    __syncthreads();
}

// ---------- radix-2 DIF (unswizzled), for the 2048-pt kernel inverse only ----------
template <int LOGN, int NT>
__device__ void fft_dif2(float2* s, int tid, float dir) {
    const int N = 1 << LOGN;
    for (int st = LOGN - 1; st >= 0; --st) {
        __syncthreads();
        int half = 1 << st;
        for (int b = tid; b < (N >> 1); b += NT) {
            int j  = b & (half - 1);
            int i0 = ((b >> st) << (st + 1)) + j;
            int i1 = i0 + half;
            float2 u = s[i0], v = s[i1];
            float2 d = make_float2(u.x - v.x, u.y - v.y);
            s[i0] = make_float2(u.x + v.x, u.y + v.y);
            if (half > 1) {
                float ang = dir * 3.14159265358979f * (float)j / (float)half;
                float c, sn;
                __sincosf(ang, &sn, &c);
                s[i1] = cmul(make_float2(c, sn), d);
            } else {
                s[i1] = d;
            }
        }
    }
    __syncthreads();
}

// ---------- prep (heterogeneous): blocks 0..511 = kf+kprep; 512..4607 = transpose_in.
// kprep emits the FULL 8192-bin kernel spectrum (Hermitian-extended, 1/8192 pre-folded)
// in conv2's slot order: slot q holds K_full[perm13(q)].  Tail works on slot PAIRS
// (q, q|1) -> bins (j, j+4096): K_full[j+4096] = conj(X[4096-j]), and X[j], X[4096-j]
// share the same Y-pair and sincos (sin(pi-t)=sin t, cos=-cos) -> one unpack per pair,
// float4 stores.  Generic formula covers q=0 (DC/Nyquist) exactly — verified: j=0 gives
// X=(Y0.x+Y0.y,0)=DC, Xc2=(Y0.x-Y0.y,0)=Nyquist. ----------
__global__ __launch_bounds__(KTPB) void prep_kernel(
    const float* __restrict__ log_dt, const float* __restrict__ w_ri,
    const float* __restrict__ Bri, const float* __restrict__ Cri,
    const float* __restrict__ x, float2* __restrict__ Kt, float* __restrict__ xt) {
    __shared__ float2 s[4096];
    __shared__ float2 kf_last;
    __shared__ float2 wds[32];
    __shared__ float aab[4][32], rab[4][32];
    __shared__ float qn[32], pn[32];
    const int tid = threadIdx.x;

    if (blockIdx.x >= 512) {
        // ---- transpose_in tile (512 threads, 2 iterations), tile buffer aliases s[]
        float* tile = (float*)s;                       // [64][65] floats = 16.6 KB
        const int tl_id = blockIdx.x - 512;            // 0..4095
        const int b  = tl_id >> 9;
        const int rem = tl_id & 511;
        const int t0 = (rem >> 3) << 6;                // 64 t-tiles
        const int h0 = (rem & 7) << 6;                 // 8 h-tiles
        const float4* xv = (const float4*)(x + ((size_t)b * 4096 + t0) * 512 + h0);
#pragma unroll
        for (int i = 0; i < 2; ++i) {
            int idx = tid + KTPB * i;                  // 0..1023
            int tl = idx >> 4, hq = idx & 15;
            float4 v = xv[(size_t)tl * 128 + hq];
            tile[tl * 65 + hq * 4 + 0] = v.x; tile[tl * 65 + hq * 4 + 1] = v.y;
            tile[tl * 65 + hq * 4 + 2] = v.z; tile[tl * 65 + hq * 4 + 3] = v.w;
        }
        __syncthreads();
        float* xo = xt + ((size_t)(b * 512 + h0)) * 4096 + t0;
#pragma unroll
        for (int i = 0; i < 2; ++i) {
            int idx = tid + KTPB * i;
            int hl = idx >> 4, tq = idx & 15;
            float4 v = make_float4(tile[(tq * 4 + 0) * 65 + hl], tile[(tq * 4 + 1) * 65 + hl],
                                   tile[(tq * 4 + 2) * 65 + hl], tile[(tq * 4 + 3) * 65 + hl]);
            ((float4*)(xo + (size_t)hl * 4096))[tq] = v;
        }
        return;
    }

    // ---- kf part (identical math; spectrum stored in kfs = s[2048..4096) + kf_last)
    const int hh = blockIdx.x;
    float2* kfs = s + 2048;
    const float dt = expf(log_dt[hh]);
    if (tid < 32) {
        float wr = w_ri[2 * tid] * dt, wi = w_ri[2 * tid + 1] * dt;
        wds[tid] = make_float2(wr, wi);
        qn[tid]  = wr * wr + wi * wi;
        pn[tid]  = -2.0f * wr;
    }
    __syncthreads();
    if (tid < 128) {
        int a = tid >> 6, b = (tid >> 5) & 1, n = tid & 31;
        const float* Cp = Cri + (((hh * 2 + a) * 32) + n) * 2;
        const float* Bp = Bri + (((hh * 2 + b) * 32) + n) * 2;
        float Cr = Cp[0], Ci = Cp[1], Br = Bp[0], Bi = Bp[1];
        float2 v = make_float2(Cr * Br + Ci * Bi, Cr * Bi - Ci * Br);  // conj(C)*B
        float2 wd = wds[n];
        aab[a * 2 + b][n] = -2.0f * (v.x * wd.x + v.y * wd.y);
        rab[a * 2 + b][n] = 2.0f * v.x;
    }
    __syncthreads();
    for (int f = tid; f < 2049; f += KTPB) {
        float th = (6.283185307179586f / 4096.0f) * (float)f;
        float cf = cosf(th), sf = sinf(th);
        float2 den = make_float2(1.0f + cf, -sf);      // 1 + freq
        float zt  = 2.0f * tanf(0.5f * th);
        float zt2 = zt * zt;
        float2 r00 = make_float2(0.f, 0.f), r01 = r00, r10 = r00, r11 = r00;
        for (int n = 0; n < 32; ++n) {
            float c   = qn[n] - zt2;
            float d   = pn[n] * zt;
            float inv = 1.0f / (c * c + d * d);
            float cc = c * inv, dd = d * inv;
            float a0 = aab[0][n], b0 = rab[0][n] * zt;
            r00.x += a0 * cc + b0 * dd; r00.y += b0 * cc - a0 * dd;
            float a1 = aab[1][n], b1 = rab[1][n] * zt;
            r01.x += a1 * cc + b1 * dd; r01.y += b1 * cc - a1 * dd;
            float a2 = aab[2][n], b2 = rab[2][n] * zt;
            r10.x += a2 * cc + b2 * dd; r10.y += b2 * cc - a2 * dd;
            float a3 = aab[3][n], b3 = rab[3][n] * zt;
            r11.x += a3 * cc + b3 * dd; r11.y += b3 * cc - a3 * dd;
        }
        r00.x *= dt; r00.y *= dt; r01.x *= dt; r01.y *= dt;
        r10.x *= dt; r10.y *= dt; r11.x *= dt; r11.y *= dt;
        float2 q  = cdivf(cmul(r01, r10), make_float2(1.0f + r11.x, r11.y));
        float2 k0 = make_float2(r00.x - q.x, r00.y - q.y);
        float2 kv = cmul(k0, cdivf(make_float2(2.0f, 0.0f), den));
        if (f < 2048) kfs[f] = kv; else kf_last = kv;
    }
    __syncthreads();

    // ---- kprep part: reads spectrum from s[2048..] / kf_last, writes s[0..2048)
    for (int m = tid; m < 2048; m += KTPB) {
        float2 Xm = kfs[m];
        float2 Xc = (m == 0) ? kf_last : kfs[2048 - m];
        if (m == 0) { Xm.y = 0.0f; Xc.y = 0.0f; }
        float2 A  = make_float2(Xm.x + Xc.x, Xm.y - Xc.y);
        float2 Bv = make_float2(Xm.x - Xc.x, Xm.y + Xc.y);
        float ang = (3.14159265358979f / 2048.0f) * (float)m;
        float c, sn;
        __sincosf(ang, &sn, &c);
        float2 O = cmul(make_float2(c, sn), Bv);
        s[m] = make_float2(0.5f * (A.x - O.y), 0.5f * (A.y + O.x));
    }
    fft_dif2<11, KTPB>(s, tid, +1.0f);  // inverse, natural-in -> bitrev-out (unswizzled)
    float2 reg[4];
    const float sc = 1.0f / 2048.0f;
#pragma unroll
    for (int i = 0; i < 4; ++i) {
        int t = tid + KTPB * i;  // 0..2047
        float2 v = s[brev11(t)];
        reg[i] = make_float2(v.x * sc, v.y * sc);
    }
    __syncthreads();
#pragma unroll
    for (int i = 0; i < 4; ++i) {
        int t = tid + KTPB * i;
        s[swz(t)]        = reg[i];
        s[swz(t + 2048)] = make_float2(0.f, 0.f);   // reclaims the dead kfs region
    }
    fft8_dif<12, KTPB>(s, tid, -1.0f);  // slot p holds Y[rev8(p)]
    float4* K4 = (float4*)(Kt + ((size_t)hh << 13));
    const float isc = 1.0f / 8192.0f;
    for (int i = 0; i < 8; ++i) {
        int qh = tid + (i << 9);        // pair index 0..4095; q = 2*qh
        int q  = qh << 1;
        int j  = ((q >> 10) & 7) | (((q >> 7) & 7) << 3) | (((q >> 4) & 7) << 6)
               | (((q >> 1) & 7) << 9);                      // perm13(q), q even -> j<4096
        int p  = rev8(j);
        int pc = rev8((4096 - j) & 4095);
        float2 Yj = s[swz(p)], Yc = s[swz(pc)];
        float2 A  = make_float2(Yj.x + Yc.x, Yj.y - Yc.y);
        float2 Bv = make_float2(Yj.x - Yc.x, Yj.y + Yc.y);
        float ang = -(3.14159265358979f / 4096.0f) * (float)j;
        float c, sn;
        __sincosf(ang, &sn, &c);
        float2 t2  = cmul(make_float2(c, sn), make_float2(Bv.y, -Bv.x));
        float2 X   = make_float2(0.5f * (A.x + t2.x), 0.5f * (A.y + t2.y));     // K_full[j]
        float2 t2c = cmul(make_float2(-c, sn), make_float2(Bv.y, Bv.x));
        float2 Xc2 = make_float2(0.5f * (A.x + t2c.x), 0.5f * (-A.y + t2c.y));  // X[4096-j]
        K4[qh] = make_float4(X.x * isc, X.y * isc, Xc2.x * isc, -Xc2.y * isc);  // [X, conj(Xc2)]
    }
}

// ---------- conv2: TWO rows per block via complex packing z = x1 + i*x2.
// y1+i*y2 = ifft8192(K * fft8192(z)) — K Hermitian => both convs in one transform.
// N=8192: radix-8 h=1024(regs,dft8z),128,16,2; the radix-2 h=1 fwd + pointwise +
// radix-2 inv are FUSED into one barrier-free thread-local pair loop (slots 2b,2b+1
// are thread-exclusive and swz13 preserves bit0 -> i1 = i0^1).  9 barriers total. ----------
__global__ __launch_bounds__(CTPB) void conv_kernel(const float* xt,
                                                    const float2* __restrict__ Kt,
                                                    const float* __restrict__ Dv,
                                                    float* yt) {
    __shared__ float2 s[8192];
    const int bp  = blockIdx.x >> 9;        // batch pair 0..3
    const int hch = blockIdx.x & 511;
    const int tid = threadIdx.x;            // 0..1023
    const int stid = swz13(tid);
    float* r1 = (float*)(xt + ((size_t)(bp * 1024 + hch)) * 4096);        // row (2bp, h)
    float* r2 = r1 + (size_t)512 * 4096;                                   // row (2bp+1, h)

    // ---- stage A fwd (DIF h=1024) in registers; upper half zero pad -> dft8z
    {
        float2 z[4];
#pragma unroll
        for (int k = 0; k < 4; ++k) {
            int t = tid + (k << 10);
            z[k] = make_float2(r1[t], r2[t]);
        }
        float2 y[8];
        dft8z(z[0], z[1], z[2], z[3], y, -1.0f);
        float ang = -(6.283185307179586f / 8192.0f) * (float)tid;
        float c, sn;
        __sincosf(ang, &sn, &c);
        float2 w = make_float2(c, sn), wm = w;
        s[stid] = y[0];
#pragma unroll
        for (int m = 1; m < 8; ++m) {
            s[stid ^ swz13(m << 10)] = cmul(wm, y[m]);
            wm = cmul(wm, w);
        }
    }
    dif13<7, -1>(s, tid);   // h=128
    dif13<4, -1>(s, tid);   // h=16
    dif13<1, -1>(s, tid);   // h=2
    __syncthreads();
    // ---- fused: radix-2 fwd + pointwise + radix-2 inv, thread-local pairs, no barriers
    {
        const float4* K4 = (const float4*)(Kt + ((size_t)hch << 13));
#pragma unroll
        for (int it = 0; it < 4; ++it) {
            int b  = tid + (it << 10);
            int i0 = swz13(b << 1);
            int i1 = i0 ^ 1;
            float4 kk = K4[b];               // K[2b], K[2b+1] — coalesced float4
            float2 u = s[i0], v = s[i1];
            float2 U = cmul(cadd(u, v), make_float2(kk.x, kk.y));
            float2 V = cmul(csub(u, v), make_float2(kk.z, kk.w));
            s[i0] = cadd(U, V);
            s[i1] = csub(U, V);
        }
    }
    dit13<1, 1>(s, tid);    // h=2
    dit13<4, 1>(s, tid);    // h=16
    dit13<7, 1>(s, tid);    // h=128
    __syncthreads();
    // ---- stage A inv (DIT h=1024) in registers; keep t<4096 (m<=3); fuse D*x skip
    {
        float ang = (6.283185307179586f / 8192.0f) * (float)tid;
        float c, sn;
        __sincosf(ang, &sn, &c);
        float2 w = make_float2(c, sn);
        float2 x[8];
        x[0] = s[stid];
        float2 wm = w;
#pragma unroll
        for (int k = 1; k < 8; ++k) {
            x[k] = cmul(wm, s[stid ^ swz13(k << 10)]);
            wm = cmul(wm, w);
        }
        float2 y[4];
        dft8_lo(x, y, 1.0f);
        const float D = Dv[hch];
#pragma unroll
        for (int m = 0; m < 4; ++m) {
            int t = tid + (m << 10);
            float x1 = r1[t], x2 = r2[t];   // re-read own rows; in-place per-element safe
            r1[t] = y[m].x + D * x1;        // (1/8192 pre-folded into K)
            r2[t] = y[m].y + D * x2;
        }
    }
}

// ---------- transpose out (pure): out[b,t,h] = yt[(b*512+h),t] ----------
__global__ __launch_bounds__(TPB) void transpose_out(const float* __restrict__ yt,
                                                     float* __restrict__ out) {
    __shared__ float tile[64][65];
    const int b = blockIdx.z, t0 = blockIdx.y * 64, h0 = blockIdx.x * 64;
    const int tid = threadIdx.x;
    const float* yp = yt + ((size_t)(b * 512 + h0)) * 4096 + t0;
#pragma unroll
    for (int i = 0; i < 4; ++i) {
        int idx = tid + TPB * i;
        int hl = idx >> 4, tq = idx & 15;
        float4 v = ((const float4*)(yp + (size_t)hl * 4096))[tq];
        tile[tq * 4 + 0][hl] = v.x; tile[tq * 4 + 1][hl] = v.y;
        tile[tq * 4 + 2][hl] = v.z; tile[tq * 4 + 3][hl] = v.w;
    }
    __syncthreads();
    float4* ov = (float4*)(out + ((size_t)b * 4096 + t0) * 512 + h0);
#pragma unroll
    for (int i = 0; i < 4; ++i) {
        int idx = tid + TPB * i;
        int tl = idx >> 4, hq = idx & 15;
        float4 v = make_float4(tile[tl][4 * hq + 0], tile[tl][4 * hq + 1],
                               tile[tl][4 * hq + 2], tile[tl][4 * hq + 3]);
        ov[(size_t)tl * 128 + hq] = v;
    }
}

extern "C" void kernel_launch(void* const* d_in, const int* in_sizes, int n_in,
                              void* d_out, int out_size, void* d_ws, size_t ws_size,
                              hipStream_t stream) {
    (void)in_sizes; (void)n_in; (void)out_size; (void)ws_size;
    const float* x      = (const float*)d_in[0];  // [8,4096,512]
    const float* log_dt = (const float*)d_in[1];  // [512]
    const float* w_ri   = (const float*)d_in[2];  // [32,2]
    const float* Bri    = (const float*)d_in[3];  // [512,2,32,2]
    const float* Cri    = (const float*)d_in[4];  // [512,2,32,2]
    const float* Dv     = (const float*)d_in[5];  // [512]
    float* out = (float*)d_out;

    char* ws = (char*)d_ws;
    float*  xt = (float*)(ws);                  // 8*512*4096*4 = 67,108,864 B (reused as yt)
    float2* Kt = (float2*)(ws + 67108864);      // 512*8192*8   = 33,554,432 B (end 96 MiB)

    prep_kernel<<<512 + 4096, KTPB, 0, stream>>>(log_dt, w_ri, Bri, Cri, x, Kt, xt);
    conv_kernel<<<2048, CTPB, 0, stream>>>(xt, Kt, Dv, xt);  // y(+skip) overwrites xt rows
    transpose_out<<<dim3(8, 64, 8), TPB, 0, stream>>>(xt, out);
}